// Round 4
// baseline (495.880 us; speedup 1.0000x reference)
//
#include <hip/hip_runtime.h>
#include <hip/hip_bf16.h>

// CalcSpixelFeats R4. R1-R3 all ~400us with every pipe idle (VALU ~1.7%,
// HBM ~1%, conflicts 0): fp32 LDS atomics are CAS-expanded (atomicrmw fadd
// -> cmpxchg loop; LLVM won't emit ds_add_f32 without unsafe-fp-atomics).
// Dependent ds_read/ds_cmpst chains at ~240+cy/step = latency-serialized.
// R4: identical structure to R3, ONE change: unsafeAtomicAdd -> native
// non-return ds_add_f32 (issue-limited, no chain).

#define CCH 32          // channels, fixed by problem
#define TPB 256
#define TILE 128        // pixels per tile
#define AS 33           // acc row stride (C + wsum), +1 -> bank spread
#define FS 33           // feats row stride
#define KMAX 256        // K = nw*nh = 256 for this problem

__device__ __forceinline__ void lds_fadd(float* p, float v) {
    unsafeAtomicAdd(p, v);   // ds_add_f32 (non-return) for LDS pointers
}

__global__ __launch_bounds__(TPB) void spx_accum_kernel(
    const float* __restrict__ pf,      // [B][C][P]
    const float* __restrict__ assoc,   // [B][9][P]
    const int*   __restrict__ idxmap,  // [B][P]
    const int*   __restrict__ nw_p,
    const int*   __restrict__ nh_p,
    float* __restrict__ part_f,        // [B*G][K][C]
    float* __restrict__ part_w,        // [B*G][K]
    int P, int K, int G, int ntiles)
{
    __shared__ float acc[(KMAX + 1) * AS];   // row K = dummy for invalid
    __shared__ float feat[TILE * FS];
    __shared__ uint2 bw[TILE * 9];           // {bin_row_offset, w bits}

    const int b   = blockIdx.x / G;
    const int g   = blockIdx.x % G;
    const int tid = threadIdx.x;
    const int nw  = nw_p[0];
    const int nh  = nh_p[0];

    for (int i = tid; i < (KMAX + 1) * AS; i += TPB) acc[i] = 0.0f;
    __syncthreads();

    const float* pf_b = pf     + (size_t)b * CCH * P;
    const float* as_b = assoc  + (size_t)b * 9 * P;
    const int*   ix_b = idxmap + (size_t)b * P;

    const int pl = tid & (TILE - 1);   // pixel lane within tile
    const int hh = tid >> 7;           // half: 0 or 1
    const int c  = tid & 31;           // channel lane (phase B)
    const int q  = tid >> 5;           // pixel group 0..7 (phase B)

    for (int tile = g; tile < ntiles; tile += G) {
        const int p0 = tile * TILE;
        const int p  = p0 + pl;
        const bool pin = (p < P);

        // ---- Phase A: stage tile into LDS (coalesced global loads) ----
#pragma unroll
        for (int cc = 0; cc < 16; ++cc) {
            const int ch = hh * 16 + cc;
            feat[pl * FS + ch] = pin ? pf_b[(size_t)ch * P + p] : 0.0f;
        }
        const int idx = pin ? ix_b[p] : 0;
        const int iy  = idx / nw;
        const int ixx = idx - iy * nw;
#pragma unroll
        for (int j = 0; j < 9; ++j) {
            if ((j & 1) == hh) {
                const int dy = j / 3 - 1;
                const int dx = j % 3 - 1;
                const int ty = iy + dy;
                const int tx = ixx + dx;
                const bool valid =
                    (tx >= 0) & (tx < nw) & (ty >= 0) & (ty < nh) & pin;
                const float wj  = (pin ? as_b[(size_t)j * P + p] : 0.0f);
                const float wv  = valid ? wj : 0.0f;
                const int   off = valid ? (ty * nw + tx) * AS : K * AS;
                bw[pl * 9 + j] = make_uint2((unsigned)off, __float_as_uint(wv));
                lds_fadd(&acc[off + CCH], wv);   // wsum
            }
        }
        __syncthreads();

        // ---- Phase B: channel-in-lane accumulate ----
        for (int pp = q; pp < TILE; pp += 8) {
            const float f = feat[pp * FS + c];
#pragma unroll
            for (int j = 0; j < 9; ++j) {
                const uint2 e  = bw[pp * 9 + j];
                const float wj = __uint_as_float(e.y);
                lds_fadd(&acc[e.x + c], wj * f);
            }
        }
        __syncthreads();
    }

    // ---- Flush partials, coalesced ----
    float* pfo = part_f + (size_t)blockIdx.x * K * CCH;
    for (int i = tid; i < K * CCH; i += TPB) {
        const int t  = i >> 5;
        const int cc = i & 31;
        pfo[i] = acc[t * AS + cc];
    }
    float* pwo = part_w + (size_t)blockIdx.x * K;
    for (int i = tid; i < K; i += TPB) pwo[i] = acc[i * AS + CCH];
}

// One block per (b, t): 256 threads = 8 g-lanes x 32 channels.
__global__ __launch_bounds__(256) void spx_finalize_kernel(
    const float* __restrict__ part_f,  // [B*G][K][C]
    const float* __restrict__ part_w,  // [B*G][K]
    float* __restrict__ out,           // [B][C][K]
    int K, int G)
{
    const int b   = blockIdx.x / K;
    const int t   = blockIdx.x % K;
    const int tid = threadIdx.x;
    const int c   = tid & 31;
    const int g0  = tid >> 5;          // 0..7

    float fs = 0.0f, ws = 0.0f;
    for (int g = g0; g < G; g += 8) {
        const size_t row = (size_t)(b * G + g) * K + t;
        fs += part_f[row * CCH + c];
        ws += part_w[row];
    }

    __shared__ float redf[8][AS];
    redf[g0][c] = fs;
    if (c == 0) redf[g0][CCH] = ws;
    __syncthreads();

    if (tid < CCH) {
        float F = 0.0f, W = 0.0f;
#pragma unroll
        for (int r = 0; r < 8; ++r) {
            F += redf[r][tid];
            W += redf[r][CCH];
        }
        const float res = (W > 1e-16f) ? (F / W) : 0.0f;
        out[((size_t)b * CCH + tid) * K + t] = res;
    }
}

extern "C" void kernel_launch(void* const* d_in, const int* in_sizes, int n_in,
                              void* d_out, int out_size, void* d_ws, size_t ws_size,
                              hipStream_t stream) {
    const float* pf     = (const float*)d_in[0];
    const float* assoc  = (const float*)d_in[1];
    const int*   idxmap = (const int*)d_in[2];
    const int*   nw_p   = (const int*)d_in[3];
    const int*   nh_p   = (const int*)d_in[4];
    float* out = (float*)d_out;

    const int BP = in_sizes[2];          // B*P = 262144
    const int B  = 4;                    // fixed by reference setup
    const int P  = BP / B;               // 65536
    const int K  = out_size / (B * CCH); // 256 (== KMAX)

    int G = 128;                         // partial blocks per batch
    while (G > 8 &&
           (size_t)B * G * K * (CCH + 1) * sizeof(float) > ws_size) {
        G >>= 1;
    }
    const int ntiles = (P + TILE - 1) / TILE;

    float* part_f = (float*)d_ws;                       // [B*G][K][C]
    float* part_w = part_f + (size_t)B * G * K * CCH;   // [B*G][K]

    spx_accum_kernel<<<B * G, TPB, 0, stream>>>(
        pf, assoc, idxmap, nw_p, nh_p, part_f, part_w, P, K, G, ntiles);

    spx_finalize_kernel<<<B * K, 256, 0, stream>>>(
        part_f, part_w, out, K, G);
}

// Round 5
// 220.452 us; speedup vs baseline: 2.2494x; 2.2494x over previous
//
#include <hip/hip_runtime.h>
#include <hip/hip_bf16.h>

// CalcSpixelFeats R5: atomic-free gather formulation.
// R1-R4 post-mortem: every scatter variant pinned at ~400us with all pipes
// idle; per-CU arithmetic shows ~220 cy per LDS fp-atomic = dependent RMW
// chain latency, invariant to occupancy/layout. So: no fp atomics at all.
//  K0 memset: zero bucket counters (4KB).
//  K1 prep:  transpose-pack feats [B][C][P]fp32 -> [B][P][16]u32 (bf16 pairs,
//            coalesced both sides) + bucket scatter: list of pixel ids per
//            (b, base-bin) via native int atomics.
//  K2 gather: block owns output bin (b,k); stages its 9 neighbor buckets'
//            pixel lists into LDS, threads (ch-pair x 16 pixel-groups)
//            accumulate w*f in REGISTERS, LDS tree-reduce, write out[b][c][k].
// bf16 feat quantization: ~2^-9 rel err, randomized over ~2300-pixel sums
// -> ~3e-5 output error, threshold 2.37e-3.

#define CCH 32          // channels, fixed by problem
#define TPB 256
#define MAXPP 512       // bucket capacity; mean load 256, sd 16 -> 16 sigma

__device__ __forceinline__ unsigned pack_bf16(float a, float b) {
    unsigned ua = __float_as_uint(a);
    unsigned ub = __float_as_uint(b);
    ua = (ua + 0x7FFFu + ((ua >> 16) & 1u)) >> 16;   // RNE
    ub = (ub + 0x7FFFu + ((ub >> 16) & 1u)) >> 16;
    return ua | (ub << 16);
}

__global__ __launch_bounds__(TPB) void spx_prep_kernel(
    const float* __restrict__ pf,      // [B][C][P]
    const int*   __restrict__ idxmap,  // [B][P]
    unsigned*    __restrict__ pfT,     // [B*P][16] bf16 pairs
    int*         __restrict__ cnt,     // [B*K]
    int*         __restrict__ list,    // [B*K][maxpp]
    int P, int K, int cpb, int maxpp)  // cpb = P/TPB chunks per batch
{
    const int b = blockIdx.x / cpb;
    const int p = (blockIdx.x % cpb) * TPB + threadIdx.x;
    const float* pf_b = pf + (size_t)b * CCH * P;

    float f[CCH];
#pragma unroll
    for (int c = 0; c < CCH; ++c) f[c] = pf_b[(size_t)c * P + p];  // coalesced

    unsigned u[16];
#pragma unroll
    for (int c2 = 0; c2 < 16; ++c2) u[c2] = pack_bf16(f[2*c2], f[2*c2+1]);

    uint4* dst = (uint4*)(pfT + ((size_t)b * P + p) * 16);
#pragma unroll
    for (int s = 0; s < 4; ++s)
        dst[s] = make_uint4(u[4*s], u[4*s+1], u[4*s+2], u[4*s+3]);

    const int idx = idxmap[(size_t)b * P + p];
    const int pos = atomicAdd(&cnt[b * K + idx], 1);   // native int atomic
    if (pos < maxpp) list[(b * K + idx) * maxpp + pos] = p;
}

__global__ __launch_bounds__(TPB) void spx_gather_kernel(
    const float*    __restrict__ assoc,   // [B][9][P]
    const unsigned* __restrict__ pfT,     // [B*P][16]
    const int*      __restrict__ cnt,     // [B*K]
    const int*      __restrict__ list,    // [B*K][maxpp]
    const int*      __restrict__ nw_p,
    const int*      __restrict__ nh_p,
    float*          __restrict__ out,     // [B][C][K]
    int P, int K, int maxpp)
{
    __shared__ unsigned plist[9 * MAXPP];          // 18 KB
    __shared__ int   jcnt[9], jbase[9], pref[10];
    __shared__ float red[16][CCH + 1];

    const int b   = blockIdx.x / K;
    const int k   = blockIdx.x - b * K;
    const int tid = threadIdx.x;
    const int nw  = nw_p[0];
    const int nh  = nh_p[0];
    const int ky  = k / nw;
    const int kx  = k - ky * nw;

    if (tid < 9) {
        const int dy = tid / 3 - 1, dx = tid % 3 - 1;
        const int sy = ky - dy, sx = kx - dx;      // source base bin
        const bool v = (sx >= 0) & (sx < nw) & (sy >= 0) & (sy < nh);
        const int src = v ? (sy * nw + sx) : 0;
        int c = v ? cnt[b * K + src] : 0;
        if (c > maxpp) c = maxpp;
        jcnt[tid]  = c;
        jbase[tid] = (b * K + src) * maxpp;
    }
    __syncthreads();
    if (tid == 0) {
        int s = 0;
#pragma unroll
        for (int j = 0; j < 9; ++j) { pref[j] = s; s += jcnt[j]; }
        pref[9] = s;
    }
    __syncthreads();

    // stage lists into LDS, tagged with plane j (p < 2^17)
#pragma unroll
    for (int j = 0; j < 9; ++j) {
        const int c = jcnt[j], base = jbase[j], o = pref[j];
        for (int i = tid; i < c; i += TPB)
            plist[o + i] = ((unsigned)j << 17) | (unsigned)list[base + i];
    }
    __syncthreads();

    const int ntot = pref[9];
    const int ch2  = tid & 15;      // channel pair
    const int q    = tid >> 4;      // pixel group 0..15
    const float*    as_b = assoc + (size_t)b * 9 * P;
    const unsigned* pfb  = pfT + (size_t)b * P * 16;

    float a0 = 0.f, a1 = 0.f, wacc = 0.f;
#pragma unroll 4
    for (int i = q; i < ntot; i += 16) {
        const unsigned e = plist[i];               // LDS broadcast per group
        const int j = (int)(e >> 17);
        const int p = (int)(e & 0x1FFFFu);
        const float w = as_b[(size_t)j * P + p];   // uniform in group
        const unsigned u = pfb[(size_t)p * 16 + ch2];  // 64B/group
        const float f0 = __uint_as_float(u << 16);
        const float f1 = __uint_as_float(u & 0xFFFF0000u);
        a0   += w * f0;
        a1   += w * f1;
        wacc += w;
    }

    red[q][2 * ch2]     = a0;
    red[q][2 * ch2 + 1] = a1;
    if (ch2 == 0) red[q][CCH] = wacc;
    __syncthreads();

    if (tid < CCH) {
        float F = 0.f, W = 0.f;
#pragma unroll
        for (int r = 0; r < 16; ++r) { F += red[r][tid]; W += red[r][CCH]; }
        const float res = (W > 1e-16f) ? (F / W) : 0.f;
        out[((size_t)b * CCH + tid) * K + k] = res;
    }
}

extern "C" void kernel_launch(void* const* d_in, const int* in_sizes, int n_in,
                              void* d_out, int out_size, void* d_ws, size_t ws_size,
                              hipStream_t stream) {
    const float* pf     = (const float*)d_in[0];
    const float* assoc  = (const float*)d_in[1];
    const int*   idxmap = (const int*)d_in[2];
    const int*   nw_p   = (const int*)d_in[3];
    const int*   nh_p   = (const int*)d_in[4];
    float* out = (float*)d_out;

    const int BP = in_sizes[2];          // B*P = 262144
    const int B  = 4;                    // fixed by reference setup
    const int P  = BP / B;               // 65536
    const int K  = out_size / (B * CCH); // 256

    // workspace layout
    const size_t pfT_bytes = (size_t)BP * 16 * sizeof(unsigned);   // 16 MB
    const size_t cnt_bytes = (size_t)B * K * sizeof(int);          // 4 KB
    unsigned* pfT = (unsigned*)d_ws;
    int* cnt  = (int*)((char*)d_ws + pfT_bytes);
    int* list = (int*)((char*)d_ws + pfT_bytes + cnt_bytes);

    // bucket capacity, clamped to available workspace
    size_t avail = (ws_size > pfT_bytes + cnt_bytes)
                       ? (ws_size - pfT_bytes - cnt_bytes) : 0;
    int maxpp = (int)(avail / ((size_t)B * K * sizeof(int)));
    if (maxpp > MAXPP) maxpp = MAXPP;
    if (maxpp < 1) maxpp = 1;

    hipMemsetAsync(cnt, 0, cnt_bytes, stream);

    const int cpb = P / TPB;             // 256 chunks per batch
    spx_prep_kernel<<<B * cpb, TPB, 0, stream>>>(
        pf, idxmap, pfT, cnt, list, P, K, cpb, maxpp);

    spx_gather_kernel<<<B * K, TPB, 0, stream>>>(
        assoc, pfT, cnt, list, nw_p, nh_p, out, P, K, maxpp);
}

// Round 6
// 183.178 us; speedup vs baseline: 2.7071x; 1.2035x over previous
//
#include <hip/hip_runtime.h>
#include <hip/hip_bf16.h>

// CalcSpixelFeats R6.
// R5 post-mortem: prep 90us @ 6% HBM (grid-limited to 4 blocks/CU + 262K
// contended global atomics); gather reads assoc at random p -> ~150MB line
// amplification. R6:
//  - prep mega-grid (2048 blocks): 1024 transpose-pack blocks + 1024 bucket
//    blocks (full 32-wave/CU residency, streaming overlaps atomic latency).
//    Bucket blocks read the 9 assoc planes COALESCED and store per-(bucket,j)
//    weight columns alongside the pixel list -> gather needs no assoc at all.
//  - gather: 512 thr/block, stages {p,w} pairs to LDS (all coalesced reads),
//    register accumulate, LDS reduce, direct out. Only pfT (16MB, LLC) is
//    gathered at 64B/pixel-visit granularity.

#define CCH  32         // channels, fixed by problem
#define TPB  256        // prep block
#define GTPB 512        // gather block
#define CAPC 448        // bucket capacity (mean 256, sd 16 -> +12 sigma)
#define KMAX 256

__device__ __forceinline__ unsigned pack_bf16(float a, float b) {
    unsigned ua = __float_as_uint(a);
    unsigned ub = __float_as_uint(b);
    ua = (ua + 0x7FFFu + ((ua >> 16) & 1u)) >> 16;   // RNE
    ub = (ub + 0x7FFFu + ((ub >> 16) & 1u)) >> 16;
    return ua | (ub << 16);
}

__global__ __launch_bounds__(TPB) void spx_prep_kernel(
    const float* __restrict__ pf,      // [B][C][P]
    const float* __restrict__ assoc,   // [B][9][P]
    const int*   __restrict__ idxmap,  // [B][P]
    unsigned*    __restrict__ pfT,     // [B*P][16] bf16 pairs
    int*         __restrict__ cnt,     // [B*K]
    int*         __restrict__ list_p,  // [B*K][cap]
    float*       __restrict__ wcol,    // [B*K][9][cap]
    int P, int K, int cap, int ncb, int cpb)
{
    const int role = blockIdx.x / ncb;          // 0: transpose, 1: bucket
    const int bi   = blockIdx.x - role * ncb;
    const int b    = bi / cpb;
    const int p    = (bi - b * cpb) * TPB + threadIdx.x;

    if (role == 0) {
        // ---- transpose-pack: [B][C][P] fp32 -> [B*P][16] bf16-pairs ----
        const float* pf_b = pf + (size_t)b * CCH * P;
        float f[CCH];
#pragma unroll
        for (int c = 0; c < CCH; ++c) f[c] = pf_b[(size_t)c * P + p];
        unsigned u[16];
#pragma unroll
        for (int c2 = 0; c2 < 16; ++c2) u[c2] = pack_bf16(f[2*c2], f[2*c2+1]);
        uint4* dst = (uint4*)(pfT + ((size_t)b * P + p) * 16);
#pragma unroll
        for (int s = 0; s < 4; ++s)
            dst[s] = make_uint4(u[4*s], u[4*s+1], u[4*s+2], u[4*s+3]);
    } else {
        // ---- bucket build: pixel id + 9 weights into base-bin bucket ----
        const float* as_b = assoc + (size_t)b * 9 * P;
        const int idx = idxmap[(size_t)b * P + p];
        float wv[9];
#pragma unroll
        for (int j = 0; j < 9; ++j) wv[j] = as_b[(size_t)j * P + p]; // coalesced
        const int bkt = b * K + idx;
        const int pos = atomicAdd(&cnt[bkt], 1);
        if (pos < cap) {
            list_p[(size_t)bkt * cap + pos] = p;
#pragma unroll
            for (int j = 0; j < 9; ++j)
                wcol[((size_t)bkt * 9 + j) * cap + pos] = wv[j];
        }
    }
}

// Block owns output bin (b,k). 512 thr = 16 ch-pair lanes x 32 pixel groups.
__global__ __launch_bounds__(GTPB) void spx_gather_kernel(
    const unsigned* __restrict__ pfT,     // [B*P][16]
    const int*      __restrict__ cnt,     // [B*K]
    const int*      __restrict__ list_p,  // [B*K][cap]
    const float*    __restrict__ wcol,    // [B*K][9][cap]
    const int*      __restrict__ nw_p,
    const int*      __restrict__ nh_p,
    float*          __restrict__ out,     // [B][C][K]
    int P, int K, int cap)
{
    __shared__ uint2 plist[9 * CAPC];     // {pixel, w bits} — 32.3 KB
    __shared__ int   jcnt[9], jsrc[9], pref[10];
    __shared__ float red[32][CCH + 1];

    const int b   = blockIdx.x / K;
    const int k   = blockIdx.x - b * K;
    const int tid = threadIdx.x;
    const int nw  = nw_p[0];
    const int nh  = nh_p[0];
    const int ky  = k / nw;
    const int kx  = k - ky * nw;

    if (tid < 9) {
        const int dy = tid / 3 - 1, dx = tid % 3 - 1;
        const int sy = ky - dy, sx = kx - dx;      // source base bin
        const bool v = (sx >= 0) & (sx < nw) & (sy >= 0) & (sy < nh);
        const int src = v ? (b * K + sy * nw + sx) : 0;
        int c = v ? cnt[src] : 0;
        if (c > cap) c = cap;
        jcnt[tid] = c;
        jsrc[tid] = src;
    }
    __syncthreads();
    if (tid == 0) {
        int s = 0;
#pragma unroll
        for (int j = 0; j < 9; ++j) { pref[j] = s; s += jcnt[j]; }
        pref[9] = s;
    }
    __syncthreads();

    // stage {p, w} into LDS — all global reads coalesced
#pragma unroll
    for (int j = 0; j < 9; ++j) {
        const int c = jcnt[j], o = pref[j], sb = jsrc[j];
        const int*   lp = list_p + (size_t)sb * cap;
        const float* wc = wcol + ((size_t)sb * 9 + j) * cap;
        for (int i = tid; i < c; i += GTPB)
            plist[o + i] = make_uint2((unsigned)lp[i], __float_as_uint(wc[i]));
    }
    __syncthreads();

    const int ntot = pref[9];
    const int ch2  = tid & 15;      // channel pair
    const int q    = tid >> 4;      // pixel group 0..31
    const unsigned* pfb = pfT + (size_t)b * P * 16;

    float a0 = 0.f, a1 = 0.f, wacc = 0.f;
#pragma unroll 4
    for (int i = q; i < ntot; i += 32) {
        const uint2 e = plist[i];                    // LDS broadcast per group
        const int   p = (int)e.x;
        const float w = __uint_as_float(e.y);
        const unsigned u = pfb[(size_t)p * 16 + ch2];  // 64B/group, LLC
        a0   += w * __uint_as_float(u << 16);
        a1   += w * __uint_as_float(u & 0xFFFF0000u);
        wacc += w;
    }

    red[q][2 * ch2]     = a0;
    red[q][2 * ch2 + 1] = a1;
    if (ch2 == 0) red[q][CCH] = wacc;
    __syncthreads();

    if (tid < CCH) {
        float F = 0.f, W = 0.f;
#pragma unroll
        for (int r = 0; r < 32; ++r) { F += red[r][tid]; W += red[r][CCH]; }
        const float res = (W > 1e-16f) ? (F / W) : 0.f;
        out[((size_t)b * CCH + tid) * K + k] = res;
    }
}

extern "C" void kernel_launch(void* const* d_in, const int* in_sizes, int n_in,
                              void* d_out, int out_size, void* d_ws, size_t ws_size,
                              hipStream_t stream) {
    const float* pf     = (const float*)d_in[0];
    const float* assoc  = (const float*)d_in[1];
    const int*   idxmap = (const int*)d_in[2];
    const int*   nw_p   = (const int*)d_in[3];
    const int*   nh_p   = (const int*)d_in[4];
    float* out = (float*)d_out;

    const int BP = in_sizes[2];          // B*P = 262144
    const int B  = 4;                    // fixed by reference setup
    const int P  = BP / B;               // 65536
    const int K  = out_size / (B * CCH); // 256

    // workspace: pfT [16.8MB] | cnt [4KB] | list_p [B*K*cap] | wcol [B*K*9*cap]
    const size_t pfT_bytes = (size_t)BP * 16 * sizeof(unsigned);
    const size_t cnt_bytes = (size_t)B * K * sizeof(int);
    unsigned* pfT = (unsigned*)d_ws;
    int* cnt = (int*)((char*)d_ws + pfT_bytes);

    size_t avail = (ws_size > pfT_bytes + cnt_bytes)
                       ? (ws_size - pfT_bytes - cnt_bytes) : 0;
    int cap = (int)(avail / ((size_t)B * K * 10 * sizeof(int)));
    if (cap > CAPC) cap = CAPC;
    if (cap < 1) cap = 1;

    int*   list_p = (int*)((char*)cnt + cnt_bytes);
    float* wcol   = (float*)(list_p + (size_t)B * K * cap);

    hipMemsetAsync(cnt, 0, cnt_bytes, stream);

    const int cpb = P / TPB;             // 256
    const int ncb = B * cpb;             // 1024
    spx_prep_kernel<<<2 * ncb, TPB, 0, stream>>>(
        pf, assoc, idxmap, pfT, cnt, list_p, wcol, P, K, cap, ncb, cpb);

    spx_gather_kernel<<<B * K, GTPB, 0, stream>>>(
        pfT, cnt, list_p, wcol, nw_p, nh_p, out, P, K, cap);
}